// Round 1
// baseline (136.933 us; speedup 1.0000x reference)
//
#include <hip/hip_runtime.h>
#include <hip/hip_bf16.h>

// Problem constants (match reference)
constexpr int KST  = 12;    // K_STEPS
constexpr int NN   = 10;    // NUM_NEG
constexpr int B    = 2;
constexpr int C    = 512;
constexpr int T    = 4096;
constexpr int BAND = KST;   // 12 diagonals
constexpr int ROWS = BAND + NN; // 22

__device__ __forceinline__ float logsig(float x) {
    // log(sigmoid(x)) = min(x,0) - log1p(exp(-|x|))
    return fminf(x, 0.0f) - log1pf(expf(-fabsf(x)));
}

// ---------------------------------------------------------------------------
// Kernel 1: c[b] = W @ fc[b] + bias   (M=C=512, K=C=512, N=T=4096 per batch)
// Classic 64x64 tile, BK=16, 256 threads, 4x4 per thread, fp32.
// ---------------------------------------------------------------------------
constexpr int BM = 64, BN = 64, BK = 16;

__global__ __launch_bounds__(256) void gemm_linear(
    const float* __restrict__ W, const float* __restrict__ FC,
    const float* __restrict__ bias, float* __restrict__ Cout)
{
    const int b  = blockIdx.z;
    const int n0 = blockIdx.x * BN;
    const int m0 = blockIdx.y * BM;
    const float* Bp = FC + (size_t)b * C * T;
    float* Cp = Cout + (size_t)b * C * T;

    __shared__ float As[BK][BM];   // [k][m]
    __shared__ float Bs[BK][BN];   // [k][n]

    const int tid = threadIdx.x;
    const int tx = tid & 15;       // 0..15 -> n
    const int ty = tid >> 4;       // 0..15 -> m

    float acc[4][4] = {};

    for (int k0 = 0; k0 < C; k0 += BK) {
        // A tile 64x16: thread -> m = tid/4, kk0 = (tid%4)*4
        {
            const int m  = tid >> 2;
            const int kk = (tid & 3) * 4;
            const float4 v = *(const float4*)&W[(size_t)(m0 + m) * C + k0 + kk];
            As[kk + 0][m] = v.x;
            As[kk + 1][m] = v.y;
            As[kk + 2][m] = v.z;
            As[kk + 3][m] = v.w;
        }
        // B tile 16x64: thread -> kk = tid/16, n = (tid%16)*4 (coalesced)
        {
            const int kk = tid >> 4;
            const int n  = (tid & 15) * 4;
            *(float4*)&Bs[kk][n] =
                *(const float4*)&Bp[(size_t)(k0 + kk) * T + n0 + n];
        }
        __syncthreads();
        #pragma unroll
        for (int kk = 0; kk < BK; ++kk) {
            float a[4], bb[4];
            *(float4*)a  = *(const float4*)&As[kk][ty * 4];
            *(float4*)bb = *(const float4*)&Bs[kk][tx * 4];
            #pragma unroll
            for (int i = 0; i < 4; ++i)
                #pragma unroll
                for (int j = 0; j < 4; ++j)
                    acc[i][j] += a[i] * bb[j];
        }
        __syncthreads();
    }

    #pragma unroll
    for (int i = 0; i < 4; ++i) {
        const int m = m0 + ty * 4 + i;
        const float bv = bias[m];
        float4 v;
        v.x = acc[i][0] + bv;
        v.y = acc[i][1] + bv;
        v.z = acc[i][2] + bv;
        v.w = acc[i][3] + bv;
        *(float4*)&Cp[(size_t)m * T + n0 + tx * 4] = v;
    }
}

// ---------------------------------------------------------------------------
// Kernel 2: band entries + first-10-row entries.
//   cont[b,t,s] = sum_d enc[b,d,t] * c[b,d,s]
// Block: 512 threads = 8 d-groups x 64 s-lanes. Each group accumulates 64 d's,
// then LDS reduce over groups, apply log_sigmoid.
//   rows 0..11  -> positives: atomicAdd(out, logsig(v)) when s+k < T
//   rows 12..21 -> negls[b][n][s] = logsig(-v)
// ---------------------------------------------------------------------------
__global__ __launch_bounds__(512) void band_kernel(
    const float* __restrict__ enc, const float* __restrict__ Cc,
    float* __restrict__ negls, float* __restrict__ out)
{
    const int b  = blockIdx.y;
    const int s0 = blockIdx.x * 64;
    const int j  = threadIdx.x & 63;
    const int g  = threadIdx.x >> 6;  // 0..7
    const int s  = s0 + j;

    const size_t base = (size_t)b * C * T;
    const float* encb = enc + base;
    const float* Ccb  = Cc + base;

    float acc[ROWS];
    #pragma unroll
    for (int r = 0; r < ROWS; ++r) acc[r] = 0.0f;

    for (int dd = 0; dd < C / 8; ++dd) {
        const int d = g * (C / 8) + dd;
        const float* er = encb + (size_t)d * T;
        const float cc = Ccb[(size_t)d * T + s];
        #pragma unroll
        for (int k = 0; k < BAND; ++k) {
            int t = s + k;
            t = (t < T) ? t : (T - 1);   // clamp; invalid rows masked later
            acc[k] += er[t] * cc;
        }
        #pragma unroll
        for (int n = 0; n < NN; ++n) {
            acc[BAND + n] += er[n] * cc;
        }
    }

    __shared__ float red[8][ROWS][64];
    __shared__ float posacc;
    #pragma unroll
    for (int r = 0; r < ROWS; ++r) red[g][r][j] = acc[r];
    if (threadIdx.x == 0) posacc = 0.0f;
    __syncthreads();

    float mypos = 0.0f;
    for (int oid = threadIdx.x; oid < ROWS * 64; oid += 512) {
        const int r  = oid >> 6;
        const int jj = oid & 63;
        float v = 0.0f;
        #pragma unroll
        for (int gg = 0; gg < 8; ++gg) v += red[gg][r][jj];
        const int ss = s0 + jj;
        if (r < BAND) {
            if (ss + r < T) mypos += logsig(v);
        } else {
            negls[((size_t)b * NN + (r - BAND)) * T + ss] = logsig(-v);
        }
    }

    // block reduction of mypos
    #pragma unroll
    for (int off = 32; off > 0; off >>= 1)
        mypos += __shfl_down(mypos, off, 64);
    if ((threadIdx.x & 63) == 0) atomicAdd(&posacc, mypos);
    __syncthreads();
    if (threadIdx.x == 0) atomicAdd(out, posacc);
}

// ---------------------------------------------------------------------------
// Kernel 3: gather negatives.
//   neg[b,n,t] (step k) = cont[b, n, neg_idx[k,t,n]]
//   out += NUM_NEG * sum logsig(-neg) = NUM_NEG * sum negls[b][n][idx]
// ---------------------------------------------------------------------------
__global__ __launch_bounds__(256) void gather_kernel(
    const int* __restrict__ nidx, const float* __restrict__ negls,
    float* __restrict__ out)
{
    const int total = KST * T * NN;
    float local = 0.0f;
    for (int i = blockIdx.x * blockDim.x + threadIdx.x; i < total;
         i += gridDim.x * blockDim.x) {
        const int n   = i % NN;        // layout [k][t][n], n fastest
        const int idx = nidx[i];
        local += negls[(size_t)n * T + idx]          // b = 0
               + negls[(size_t)(NN + n) * T + idx];  // b = 1
    }
    #pragma unroll
    for (int off = 32; off > 0; off >>= 1)
        local += __shfl_down(local, off, 64);
    __shared__ float wsum[4];
    const int lane = threadIdx.x & 63, w = threadIdx.x >> 6;
    if (lane == 0) wsum[w] = local;
    __syncthreads();
    if (threadIdx.x == 0) {
        atomicAdd(out, (float)NN * (wsum[0] + wsum[1] + wsum[2] + wsum[3]));
    }
}

// ---------------------------------------------------------------------------
extern "C" void kernel_launch(void* const* d_in, const int* in_sizes, int n_in,
                              void* d_out, int out_size, void* d_ws, size_t ws_size,
                              hipStream_t stream)
{
    const float* enc  = (const float*)d_in[0];  // feat_enc   [B,C,T]
    const float* fc   = (const float*)d_in[1];  // feat_context [B,C,T]
    const float* W    = (const float*)d_in[2];  // [C,C]
    const float* bias = (const float*)d_in[3];  // [C]
    const int*   nidx = (const int*)d_in[4];    // [KST,T,NN]
    float* out = (float*)d_out;

    float* c_buf = (float*)d_ws;                        // B*C*T floats (16 MiB)
    float* negls = c_buf + (size_t)B * C * T;           // B*NN*T floats (320 KiB)

    hipMemsetAsync(out, 0, sizeof(float), stream);

    gemm_linear<<<dim3(T / BN, C / BM, B), 256, 0, stream>>>(W, fc, bias, c_buf);
    band_kernel<<<dim3(T / 64, B), 512, 0, stream>>>(enc, c_buf, negls, out);
    gather_kernel<<<1920, 256, 0, stream>>>(nidx, negls, out);
}

// Round 2
// 107.719 us; speedup vs baseline: 1.2712x; 1.2712x over previous
//
#include <hip/hip_runtime.h>
#include <hip/hip_bf16.h>

constexpr int KST  = 12;
constexpr int NN   = 10;
constexpr int B    = 2;
constexpr int C    = 512;
constexpr int T    = 4096;
constexpr int BAND = KST;
constexpr int ROWS = BAND + NN; // 22

typedef float f32x4  __attribute__((ext_vector_type(4)));
typedef short bf16x8 __attribute__((ext_vector_type(8)));

__device__ __forceinline__ float logsig(float x) {
    return fminf(x, 0.0f) - log1pf(expf(-fabsf(x)));
}

__device__ __forceinline__ unsigned short f2bf(float f) {
    union { float f; unsigned u; } v; v.f = f;
    unsigned r = v.u + 0x7fff + ((v.u >> 16) & 1);   // RNE
    return (unsigned short)(r >> 16);
}

// ---------------------------------------------------------------------------
// Kernel 0: cast W fp32 -> bf16
// ---------------------------------------------------------------------------
__global__ __launch_bounds__(256) void cast_w(
    const float* __restrict__ W, unsigned short* __restrict__ Wh)
{
    const int i = (blockIdx.x * 256 + threadIdx.x) * 4;
    const float4 v = *(const float4*)&W[i];
    short4 o;
    o.x = (short)f2bf(v.x);
    o.y = (short)f2bf(v.y);
    o.z = (short)f2bf(v.z);
    o.w = (short)f2bf(v.w);
    *(short4*)&Wh[i] = o;
}

// ---------------------------------------------------------------------------
// Kernel 1: c[b] = W @ fc[b] + bias via bf16 MFMA.
// Grid (T/32, B), 512 threads = 8 waves. Block tile: 512m x 32n, K staged 32
// at a time. Wave w owns m in [w*64, w*64+64): 4 m-frags x 2 n-frags of
// 16x16x32. A-frags read directly from global bf16 W (L2-resident).
// B tile fp32->bf16 transposed into LDS [n][k] (row stride 40 for 16B-aligned
// ds_read_b128, ~2-way banks).
// ---------------------------------------------------------------------------
__global__ __launch_bounds__(512) void gemm_mfma(
    const unsigned short* __restrict__ Wh, const float* __restrict__ FC,
    const float* __restrict__ bias, float* __restrict__ Cout)
{
    const int b  = blockIdx.y;
    const int n0 = blockIdx.x * 32;
    const float* FCb = FC + (size_t)b * C * T;
    float* Cp = Cout + (size_t)b * C * T;

    __shared__ unsigned short Bs[32][40];

    const int tid  = threadIdx.x;
    const int lane = tid & 63;
    const int w    = tid >> 6;       // 0..7
    const int l15  = lane & 15;
    const int l4   = lane >> 4;      // 0..3
    const int mw   = w * 64;

    const int skk = tid >> 4;        // 0..31 (k row)
    const int snn = (tid & 15) * 2;  // n pair

    f32x4 acc[4][2] = {};

    const unsigned short* Abase = Wh + (size_t)(mw + l15) * C + 8 * l4;

    for (int ks = 0; ks < C / 32; ++ks) {
        const int k0 = ks * 32;
        __syncthreads();
        {
            const float2 v = *(const float2*)&FCb[(size_t)(k0 + skk) * T + n0 + snn];
            Bs[snn    ][skk] = f2bf(v.x);
            Bs[snn + 1][skk] = f2bf(v.y);
        }
        __syncthreads();

        bf16x8 bfr[2];
        #pragma unroll
        for (int j = 0; j < 2; ++j)
            bfr[j] = *(const bf16x8*)&Bs[j * 16 + l15][8 * l4];

        #pragma unroll
        for (int i = 0; i < 4; ++i) {
            const bf16x8 afr = *(const bf16x8*)(Abase + (size_t)i * 16 * C + k0);
            acc[i][0] = __builtin_amdgcn_mfma_f32_16x16x32_bf16(afr, bfr[0], acc[i][0], 0, 0, 0);
            acc[i][1] = __builtin_amdgcn_mfma_f32_16x16x32_bf16(afr, bfr[1], acc[i][1], 0, 0, 0);
        }
    }

    #pragma unroll
    for (int i = 0; i < 4; ++i) {
        #pragma unroll
        for (int r = 0; r < 4; ++r) {
            const int m = mw + i * 16 + l4 * 4 + r;
            const float bv = bias[m];
            Cp[(size_t)m * T + n0 + l15]      = acc[i][0][r] + bv;
            Cp[(size_t)m * T + n0 + 16 + l15] = acc[i][1][r] + bv;
        }
    }
}

// ---------------------------------------------------------------------------
// Kernel 2: band (12 diagonals) + first-10-row entries of cont.
// Grid (T/32, B), 512 threads = 16 d-groups x 32 s-lanes; each group 32 d's.
// ---------------------------------------------------------------------------
__global__ __launch_bounds__(512) void band_kernel(
    const float* __restrict__ enc, const float* __restrict__ Cc,
    float* __restrict__ negls, float* __restrict__ out)
{
    const int b  = blockIdx.y;
    const int s0 = blockIdx.x * 32;
    const int j  = threadIdx.x & 31;
    const int g  = threadIdx.x >> 5;   // 0..15
    const int s  = s0 + j;

    const size_t base = (size_t)b * C * T;
    const float* encb = enc + base;
    const float* Ccb  = Cc + base;

    float acc[ROWS];
    #pragma unroll
    for (int r = 0; r < ROWS; ++r) acc[r] = 0.0f;

    #pragma unroll 4
    for (int dd = 0; dd < C / 16; ++dd) {
        const int d = g * (C / 16) + dd;
        const float* er = encb + (size_t)d * T;
        const float cc = Ccb[(size_t)d * T + s];
        #pragma unroll
        for (int k = 0; k < BAND; ++k) {
            int t = s + k;
            t = (t < T) ? t : (T - 1);   // clamp; masked at reduce
            acc[k] += er[t] * cc;
        }
        #pragma unroll
        for (int n = 0; n < NN; ++n) acc[BAND + n] += er[n] * cc;
    }

    __shared__ float red[16][ROWS][32];
    __shared__ float posacc;
    #pragma unroll
    for (int r = 0; r < ROWS; ++r) red[g][r][j] = acc[r];
    if (threadIdx.x == 0) posacc = 0.0f;
    __syncthreads();

    float mypos = 0.0f;
    for (int oid = threadIdx.x; oid < ROWS * 32; oid += 512) {
        const int r  = oid >> 5;
        const int jj = oid & 31;
        float v = 0.0f;
        #pragma unroll
        for (int gg = 0; gg < 16; ++gg) v += red[gg][r][jj];
        const int ss = s0 + jj;
        if (r < BAND) {
            if (ss + r < T) mypos += logsig(v);
        } else {
            negls[((size_t)b * NN + (r - BAND)) * T + ss] = logsig(-v);
        }
    }

    #pragma unroll
    for (int off = 32; off > 0; off >>= 1)
        mypos += __shfl_down(mypos, off, 64);
    if ((threadIdx.x & 63) == 0) atomicAdd(&posacc, mypos);
    __syncthreads();
    if (threadIdx.x == 0) atomicAdd(out, posacc);
}

// ---------------------------------------------------------------------------
// Kernel 3: gather negatives; out += NN * sum logsig(-cont[b,n,idx]).
// ---------------------------------------------------------------------------
__global__ __launch_bounds__(256) void gather_kernel(
    const int* __restrict__ nidx, const float* __restrict__ negls,
    float* __restrict__ out)
{
    const int total = KST * T * NN;
    float local = 0.0f;
    for (int i = blockIdx.x * blockDim.x + threadIdx.x; i < total;
         i += gridDim.x * blockDim.x) {
        const int n   = i % NN;        // layout [k][t][n], n fastest
        const int idx = nidx[i];
        local += negls[(size_t)n * T + idx]          // b = 0
               + negls[(size_t)(NN + n) * T + idx];  // b = 1
    }
    #pragma unroll
    for (int off = 32; off > 0; off >>= 1)
        local += __shfl_down(local, off, 64);
    __shared__ float wsum[4];
    const int lane = threadIdx.x & 63, w = threadIdx.x >> 6;
    if (lane == 0) wsum[w] = local;
    __syncthreads();
    if (threadIdx.x == 0)
        atomicAdd(out, (float)NN * (wsum[0] + wsum[1] + wsum[2] + wsum[3]));
}

// ---------------------------------------------------------------------------
extern "C" void kernel_launch(void* const* d_in, const int* in_sizes, int n_in,
                              void* d_out, int out_size, void* d_ws, size_t ws_size,
                              hipStream_t stream)
{
    const float* enc  = (const float*)d_in[0];
    const float* fc   = (const float*)d_in[1];
    const float* W    = (const float*)d_in[2];
    const float* bias = (const float*)d_in[3];
    const int*   nidx = (const int*)d_in[4];
    float* out = (float*)d_out;

    float* c_buf = (float*)d_ws;                         // B*C*T fp32 (16 MiB)
    float* negls = c_buf + (size_t)B * C * T;            // B*NN*T fp32 (320 KiB)
    unsigned short* Wh = (unsigned short*)(negls + (size_t)B * NN * T); // C*C bf16

    hipMemsetAsync(out, 0, sizeof(float), stream);

    cast_w<<<C * C / (256 * 4), 256, 0, stream>>>(W, Wh);
    gemm_mfma<<<dim3(T / 32, B), 512, 0, stream>>>(Wh, fc, bias, c_buf);
    band_kernel<<<dim3(T / 32, B), 512, 0, stream>>>(enc, c_buf, negls, out);
    gather_kernel<<<1920, 256, 0, stream>>>(nidx, negls, out);
}

// Round 3
// 57.301 us; speedup vs baseline: 2.3897x; 1.8799x over previous
//
#include <hip/hip_runtime.h>
#include <hip/hip_bf16.h>

constexpr int KST  = 12;
constexpr int NN   = 10;
constexpr int B    = 2;
constexpr int C    = 512;
constexpr int T    = 4096;
constexpr int BAND = 12;

typedef float f32x4  __attribute__((ext_vector_type(4)));
typedef short bf16x8 __attribute__((ext_vector_type(8)));

__device__ __forceinline__ float logsig(float x) {
    return fminf(x, 0.0f) - log1pf(expf(-fabsf(x)));
}
__device__ __forceinline__ unsigned short f2bf(float f) {
    union { float f; unsigned u; } v; v.f = f;
    unsigned r = v.u + 0x7fff + ((v.u >> 16) & 1);   // RNE
    return (unsigned short)(r >> 16);
}

// ---------------------------------------------------------------------------
// Kernel 0: cast W fp32 -> bf16
// ---------------------------------------------------------------------------
__global__ __launch_bounds__(256) void cast_w(
    const float* __restrict__ W, unsigned short* __restrict__ Wh)
{
    const int i = (blockIdx.x * 256 + threadIdx.x) * 4;
    const float4 v = *(const float4*)&W[i];
    short4 o;
    o.x = (short)f2bf(v.x);
    o.y = (short)f2bf(v.y);
    o.z = (short)f2bf(v.z);
    o.w = (short)f2bf(v.w);
    *(short4*)&Wh[i] = o;
}

// ---------------------------------------------------------------------------
// Fused kernel: per (s-tile of 32, batch):
//   Stage A : c[:,s-tile] = W @ fc[:,s-tile] + bias   (MFMA, K=512)
//   Epi   A : c tile -> bf16 -> swizzled LDS c_t[32][512]
//   Stage T : enc window (64 cols: n0..n0+47 clamped, then t=0..15)
//             transpose-cast -> swizzled LDS A_t[64][512]
//   Stage B : D[64 x 32] = A_t * c_t^T via MFMA; diagonals k=row-col in
//             [0,12) -> pos logsig sum; rows 44..53 -> negls[b][n][s]
// Swizzle: element (row, d) at byte row*1024 + (((d>>3) ^ (row&7))<<4) + (d&7)*2
// ---------------------------------------------------------------------------
__global__ __launch_bounds__(512) void fused_kernel(
    const unsigned short* __restrict__ Wh, const float* __restrict__ FC,
    const float* __restrict__ enc, const float* __restrict__ bias,
    float* __restrict__ negls, float* __restrict__ out)
{
    const int b  = blockIdx.y;
    const int n0 = blockIdx.x * 32;

    __shared__ unsigned short Bs[2][32][40];   // fc staging [buf][s][k]
    __shared__ unsigned short c_t[32 * 512];   // swizzled [s][d] bf16
    __shared__ unsigned short A_t[64 * 512];   // swizzled [c][d] bf16
    __shared__ float posred[8];

    const int tid  = threadIdx.x;
    const int lane = tid & 63;
    const int w    = tid >> 6;       // 0..7
    const int l15  = lane & 15;
    const int l4   = lane >> 4;      // 0..3
    const int mw   = w * 64;

    const int skk = tid >> 4;        // 0..31 (k row)
    const int snn = (tid & 15) * 2;  // s pair

    const float* FCb  = FC  + (size_t)b * C * T;
    const float* encb = enc + (size_t)b * C * T;

    // ---------------- stage A ----------------
    f32x4 acc[4][2] = {};
    const unsigned short* Abase = Wh + (size_t)(mw + l15) * C + 8 * l4;

    float2 v = *(const float2*)&FCb[(size_t)skk * T + n0 + snn];
    bf16x8 afr[4];
    #pragma unroll
    for (int i = 0; i < 4; ++i) afr[i] = *(const bf16x8*)(Abase + i * 16 * C);

    Bs[0][snn][skk]     = f2bf(v.x);
    Bs[0][snn + 1][skk] = f2bf(v.y);

    int cur = 0;
    for (int ks = 0; ks < 16; ++ks) {
        __syncthreads();
        const int kn = (ks < 15) ? ks + 1 : 15;   // clamped prefetch index
        float2 vn = *(const float2*)&FCb[(size_t)(kn * 32 + skk) * T + n0 + snn];
        bf16x8 afn[4];
        #pragma unroll
        for (int i = 0; i < 4; ++i)
            afn[i] = *(const bf16x8*)(Abase + i * 16 * C + kn * 32);

        const bf16x8 bfr0 = *(const bf16x8*)&Bs[cur][l15][8 * l4];
        const bf16x8 bfr1 = *(const bf16x8*)&Bs[cur][16 + l15][8 * l4];

        #pragma unroll
        for (int i = 0; i < 4; ++i) {
            acc[i][0] = __builtin_amdgcn_mfma_f32_16x16x32_bf16(afr[i], bfr0, acc[i][0], 0, 0, 0);
            acc[i][1] = __builtin_amdgcn_mfma_f32_16x16x32_bf16(afr[i], bfr1, acc[i][1], 0, 0, 0);
        }
        // write next staging buffer after MFMAs (load latency hidden)
        Bs[cur ^ 1][snn][skk]     = f2bf(vn.x);
        Bs[cur ^ 1][snn + 1][skk] = f2bf(vn.y);
        #pragma unroll
        for (int i = 0; i < 4; ++i) afr[i] = afn[i];
        cur ^= 1;
    }

    // ---------------- epilogue A: c tile -> swizzled LDS ----------------
    #pragma unroll
    for (int i = 0; i < 4; ++i) {
        const int mb = mw + i * 16 + l4 * 4;     // d base (mult of 4)
        const float4 bv = *(const float4*)&bias[mb];
        const int g = mb >> 3;
        #pragma unroll
        for (int j = 0; j < 2; ++j) {
            const int sp = j * 16 + l15;
            ushort4 u;
            u.x = f2bf(acc[i][j][0] + bv.x);
            u.y = f2bf(acc[i][j][1] + bv.y);
            u.z = f2bf(acc[i][j][2] + bv.z);
            u.w = f2bf(acc[i][j][3] + bv.w);
            const int off = sp * 1024 + ((g ^ (sp & 7)) << 4) + ((mb & 4) << 1);
            *(ushort4*)((char*)c_t + off) = u;
        }
    }

    // ---------------- stage T: enc window transpose-cast ----------------
    // cols c: 0..47 -> t = n0 + c (clamped), 48..63 -> t = c - 48 (first 16)
    {
        const bool safe = (n0 + 48 <= T);
        const int rr    = tid >> 3;          // 0..63
        const int cbase = (tid & 7) * 8;     // 0,8,...,56
        for (int dd = 0; dd < 8; ++dd) {
            const int d = dd * 64 + rr;
            float vals[8];
            if (cbase < 48) {
                if (safe) {
                    const float* p = encb + (size_t)d * T + n0 + cbase;
                    *(float4*)&vals[0] = *(const float4*)p;
                    *(float4*)&vals[4] = *(const float4*)(p + 4);
                } else {
                    #pragma unroll
                    for (int e = 0; e < 8; ++e) {
                        int t = n0 + cbase + e;
                        t = t < T ? t : T - 1;
                        vals[e] = encb[(size_t)d * T + t];
                    }
                }
            } else {
                const float* p = encb + (size_t)d * T + (cbase - 48);
                *(float4*)&vals[0] = *(const float4*)p;
                *(float4*)&vals[4] = *(const float4*)(p + 4);
            }
            const int gd = d >> 3;
            const int dl = (d & 7) << 1;
            #pragma unroll
            for (int e = 0; e < 8; ++e) {
                const int c = cbase + e;            // c & 7 == e
                const int off = c * 1024 + ((gd ^ e) << 4) + dl;
                *(unsigned short*)((char*)A_t + off) = f2bf(vals[e]);
            }
        }
    }
    __syncthreads();

    // ---------------- stage B: band MFMA ----------------
    const int i2 = w >> 1;               // 0..3 row-frag
    const int j2 = w & 1;                // 0..1 col-frag
    const int rg = i2 * 16 + l15;        // A row 0..63
    const int ci = (rg < 44) ? rg : ((rg < 54) ? rg + 4 : 63);
    const int sr = j2 * 16 + l15;
    const char* Abyte = (const char*)A_t + ci * 1024;
    const char* Bbyte = (const char*)c_t + sr * 1024;
    const int ax = ci & 7, bx = sr & 7;

    f32x4 dacc = {};
    #pragma unroll
    for (int ks = 0; ks < 16; ++ks) {
        const int ga = ks * 4 + l4;
        const bf16x8 a2 = *(const bf16x8*)(Abyte + ((ga ^ ax) << 4));
        const bf16x8 b2 = *(const bf16x8*)(Bbyte + ((ga ^ bx) << 4));
        dacc = __builtin_amdgcn_mfma_f32_16x16x32_bf16(a2, b2, dacc, 0, 0, 0);
    }

    // ---------------- epilogue B ----------------
    float pos = 0.0f;
    const int colr = j2 * 16 + l15;
    const int scol = n0 + colr;
    #pragma unroll
    for (int r = 0; r < 4; ++r) {
        const int row = i2 * 16 + l4 * 4 + r;
        const float vv = dacc[r];
        if (row < 44) {
            const int k = row - colr;
            if (k >= 0 && k < BAND && scol + k < T) pos += logsig(vv);
        } else if (row < 54) {
            negls[((size_t)b * NN + (row - 44)) * T + scol] = logsig(-vv);
        }
    }
    #pragma unroll
    for (int off = 32; off > 0; off >>= 1) pos += __shfl_down(pos, off, 64);
    if (lane == 0) posred[w] = pos;
    __syncthreads();
    if (tid == 0) {
        float tsum = 0.0f;
        #pragma unroll
        for (int q = 0; q < 8; ++q) tsum += posred[q];
        atomicAdd(out, tsum);
    }
}

// ---------------------------------------------------------------------------
// Kernel 2: gather negatives; out += NN * sum logsig(-cont[b,n,idx]).
// ---------------------------------------------------------------------------
__global__ __launch_bounds__(256) void gather_kernel(
    const int4* __restrict__ nidx4, const float* __restrict__ negls,
    float* __restrict__ out)
{
    const int i4 = blockIdx.x * 256 + threadIdx.x;
    const int4 vv = nidx4[i4];
    const int base = i4 * 4;
    const int idxs[4] = {vv.x, vv.y, vv.z, vv.w};
    float local = 0.0f;
    #pragma unroll
    for (int e = 0; e < 4; ++e) {
        const int n = (base + e) % NN;     // layout [k][t][n], n fastest
        local += negls[(size_t)n * T + idxs[e]]
               + negls[(size_t)(NN + n) * T + idxs[e]];
    }
    #pragma unroll
    for (int off = 32; off > 0; off >>= 1) local += __shfl_down(local, off, 64);
    __shared__ float wsum[4];
    if ((threadIdx.x & 63) == 0) wsum[threadIdx.x >> 6] = local;
    __syncthreads();
    if (threadIdx.x == 0)
        atomicAdd(out, (float)NN * (wsum[0] + wsum[1] + wsum[2] + wsum[3]));
}

// ---------------------------------------------------------------------------
extern "C" void kernel_launch(void* const* d_in, const int* in_sizes, int n_in,
                              void* d_out, int out_size, void* d_ws, size_t ws_size,
                              hipStream_t stream)
{
    const float* enc  = (const float*)d_in[0];
    const float* fc   = (const float*)d_in[1];
    const float* W    = (const float*)d_in[2];
    const float* bias = (const float*)d_in[3];
    const int*   nidx = (const int*)d_in[4];
    float* out = (float*)d_out;

    unsigned short* Wh = (unsigned short*)d_ws;                       // C*C bf16
    float* negls = (float*)((char*)d_ws + (size_t)C * C * sizeof(unsigned short));

    hipMemsetAsync(out, 0, sizeof(float), stream);

    cast_w<<<C * C / (256 * 4), 256, 0, stream>>>(W, Wh);
    fused_kernel<<<dim3(T / 32, B), 512, 0, stream>>>(Wh, fc, enc, bias, negls, out);
    gather_kernel<<<KST * T * NN / (4 * 256), 256, 0, stream>>>(
        (const int4*)nidx, negls, out);
}